// Round 3
// baseline (418.055 us; speedup 1.0000x reference)
//
#include <hip/hip_runtime.h>

#define N 8192
#define D 128
#define MAXNZ 192   // row nnz ~ Binom(8192,0.01): mean 82, max over 8192 rows ~127
#define BATCH 32
#define PPAD 66     // P row stride (floats): 264B -> float2-aligned, mild 4-way conflict only

__device__ __forceinline__ float wave_reduce(float p) {
    #pragma unroll
    for (int off = 32; off > 0; off >>= 1)
        p += __shfl_xor(p, off, 64);
    return p;
}

// One wave per row. Phase 1: compact nonzeros (col,val) to LDS via ballot +
// prefix-popcount. Phase 2: batches of 32 nz; per-lane partial products are
// transposed through LDS (P[slot][lane]) so the 64->1 dot reduction is a
// serial in-register sum + ONE shuffle, instead of a 6-deep ds_bpermute chain.
__global__ __launch_bounds__(256, 4)
void gf_main_kernel(const float* __restrict__ A,
                    const float* __restrict__ W,
                    const float* __restrict__ b,
                    float* __restrict__ partials) {
    __shared__ int   s_col[4][MAXNZ];
    __shared__ float s_val[4][MAXNZ];
    __shared__ float s_P[4][BATCH][PPAD];   // ~33.8 KB
    __shared__ float s_bsum[4];

    const int lane = threadIdx.x & 63;
    const int w    = threadIdx.x >> 6;
    const int row  = blockIdx.x * 4 + w;

    const float2 bb = ((const float2*)b)[lane];
    float2 yi = ((const float2*)(W + (size_t)row * D))[lane];
    yi.x += bb.x; yi.y += bb.y;

    // ---- Phase 1: compact this row's nonzeros into LDS ----
    const float4* Arow = (const float4*)(A + (size_t)row * N);
    int cnt = 0;
    #pragma unroll 4
    for (int it = 0; it < N / 256; ++it) {
        const float4 a4 = Arow[it * 64 + lane];
        const float av[4] = {a4.x, a4.y, a4.z, a4.w};
        #pragma unroll
        for (int q = 0; q < 4; ++q) {
            const unsigned long long m = __ballot(av[q] > 0.0f);
            if (av[q] > 0.0f) {
                const int pos = cnt + __popcll(m & ((1ull << lane) - 1ull));
                if (pos < MAXNZ) {
                    s_col[w][pos] = it * 256 + lane * 4 + q;
                    s_val[w][pos] = av[q];
                }
            }
            cnt += __popcll(m);
        }
    }
    if (cnt > MAXNZ) cnt = MAXNZ;
    __syncthreads();

    // ---- Phase 2: batches of 32 nz, LDS-transpose reduction ----
    float acc = 0.0f;
    const int half = lane >> 5;    // which half of the 64 partials this lane sums
    const int sl   = lane & 31;    // slot this lane (pair) reduces

    for (int base = 0; base < cnt; base += BATCH) {
        // compute partial products for slots base..base+31, write P[k][lane]
        #pragma unroll
        for (int k = 0; k < BATCH; ++k) {
            const int slot = base + k;
            const int j = (slot < cnt) ? s_col[w][slot] : 0;  // uniform broadcast
            const float2 yj = ((const float2*)(W + (size_t)j * D))[lane];
            const float p = yi.x * (yj.x + bb.x) + yi.y * (yj.y + bb.y);
            s_P[w][k][lane] = p;
        }
        // reduce: lanes (sl, sl+32) each sum 32 partials of slot base+sl
        float ssum = 0.0f;
        const float2* prow = (const float2*)&s_P[w][sl][half * 32];
        #pragma unroll
        for (int t = 0; t < 16; ++t) {
            const float2 v = prow[t];
            ssum += v.x + v.y;
        }
        ssum += __shfl_xor(ssum, 32, 64);   // full dot for slot base+sl
        const int slot = base + sl;
        if (half == 0 && slot < cnt) {
            const float r = s_val[w][slot] - ssum;
            acc += r * r;
        }
    }

    // ---- Epilogue: 0.5*main + 0.05*||Y_row||^2, block reduce, one store ----
    const float v = 0.5f * acc + 0.05f * (yi.x * yi.x + yi.y * yi.y);
    const float total = wave_reduce(v);
    if (lane == 0) s_bsum[w] = total;
    __syncthreads();
    if (threadIdx.x == 0)
        partials[blockIdx.x] = s_bsum[0] + s_bsum[1] + s_bsum[2] + s_bsum[3];
}

// Reduce 2048 block partials -> out[0]. One block, 256 threads.
__global__ __launch_bounds__(256)
void gf_reduce_kernel(const float* __restrict__ partials, float* __restrict__ out) {
    __shared__ float s_ws[4];
    const int lane = threadIdx.x & 63;
    const int w    = threadIdx.x >> 6;
    float s = 0.0f;
    for (int i = threadIdx.x; i < N / 4; i += 256) s += partials[i];
    s = wave_reduce(s);
    if (lane == 0) s_ws[w] = s;
    __syncthreads();
    if (threadIdx.x == 0) out[0] = s_ws[0] + s_ws[1] + s_ws[2] + s_ws[3];
}

extern "C" void kernel_launch(void* const* d_in, const int* in_sizes, int n_in,
                              void* d_out, int out_size, void* d_ws, size_t ws_size,
                              hipStream_t stream) {
    const float* A = (const float*)d_in[0];
    const float* W = (const float*)d_in[1];
    const float* b = (const float*)d_in[2];
    float* out = (float*)d_out;
    float* partials = (float*)d_ws;    // 2048 floats

    gf_main_kernel<<<dim3(N / 4), dim3(256), 0, stream>>>(A, W, b, partials);
    gf_reduce_kernel<<<dim3(1), dim3(256), 0, stream>>>(partials, out);
}